// Round 1
// baseline (1059.196 us; speedup 1.0000x reference)
//
#include <hip/hip_runtime.h>

// ---------------------------------------------------------------------------
// HeterogeneousNormalizedAttentionBlock on MI355X (gfx950)
// B=4, LQ=LK=8192, E=256, H=8, D=32, NF=2, NE=4, HID=256;  M = B*LQ = 32768
// All GEMMs are (32768 x 256) @ (256 x 256)^T  -> bf16 MFMA 16x16x32.
// ---------------------------------------------------------------------------

typedef unsigned short u16;
typedef __attribute__((ext_vector_type(8))) short  bs8;    // 8 x bf16 (4 VGPR)
typedef __attribute__((ext_vector_type(4))) float  f32x4;  // MFMA acc

__device__ __forceinline__ float bf2f(u16 u) {
  union { float f; unsigned i; } c; c.i = ((unsigned)u) << 16; return c.f;
}
__device__ __forceinline__ u16 f2bf(float f) {
  union { float f; unsigned i; } c; c.f = f;
  unsigned x = c.i;
  return (u16)((x + 0x7fffu + ((x >> 16) & 1u)) >> 16);   // RNE
}
__device__ __forceinline__ unsigned pack2(float a, float b) {
  return (unsigned)f2bf(a) | ((unsigned)f2bf(b) << 16);
}

#define EPI_PLAIN 0
#define EPI_GELU  1
#define EPI_CINIT 2
#define EPI_CACC  3

// ---------------------------------------------------------------------------
// Workhorse GEMM: C(M,256) = epi(A(M,256) @ W(256,256)^T + bias)
// BM=BN=128, BK=64, 256 threads = 4 waves (2x2), each wave 64x64 (4x4 frags).
// LDS XOR-swizzled (G4): slot = row*8 + (c16 ^ (row&7)), 16B slots.
// A/B fragments use the SAME (lane,elem)->k bijection, so the HW's internal
// k order cancels; C/D layout = verified col=lane&15, row=(lane>>4)*4+reg.
// ---------------------------------------------------------------------------
template <bool AF32, int EPI>
__global__ __launch_bounds__(256, 2) void gemm256(
    const void* __restrict__ Ain, const u16* __restrict__ W,
    const float* __restrict__ bias, u16* __restrict__ outb,
    float* __restrict__ outf, const float* __restrict__ csrc,
    const float* __restrict__ scores, int expert) {
  __shared__ int4 ash[1024];  // 128 x 64 bf16, swizzled
  __shared__ int4 wsh[1024];
  const int tid = threadIdx.x;
  const int m0 = blockIdx.x * 128, n0 = blockIdx.y * 128;
  const int wave = tid >> 6, lane = tid & 63;
  const int wm = (wave >> 1) * 64, wn = (wave & 1) * 64;
  const int lr = lane & 15, lk = lane >> 4;
  f32x4 acc[4][4];
#pragma unroll
  for (int m = 0; m < 4; ++m)
#pragma unroll
    for (int n = 0; n < 4; ++n) acc[m][n] = f32x4{0.f, 0.f, 0.f, 0.f};

  const float* Af = (const float*)Ain;
  const u16*   Ab = (const u16*)Ain;

  for (int kt = 0; kt < 4; ++kt) {
    const int k0 = kt * 64;
    if (kt) __syncthreads();
    // stage A tile (128x64)
#pragma unroll
    for (int it = 0; it < 4; ++it) {
      const int s = tid + it * 256;
      const int row = s >> 3, c16 = s & 7;
      const int dst = (row << 3) | (c16 ^ (row & 7));
      const long src = (long)(m0 + row) * 256 + k0 + c16 * 8;
      int4 val;
      if constexpr (AF32) {
        const float4* p = (const float4*)(Af + src);
        const float4 x = p[0], y = p[1];
        val.x = pack2(x.x, x.y); val.y = pack2(x.z, x.w);
        val.z = pack2(y.x, y.y); val.w = pack2(y.z, y.w);
      } else {
        val = *(const int4*)(Ab + src);
      }
      ash[dst] = val;
    }
    // stage W tile (128x64), pre-converted bf16
#pragma unroll
    for (int it = 0; it < 4; ++it) {
      const int s = tid + it * 256;
      const int row = s >> 3, c16 = s & 7;
      const int dst = (row << 3) | (c16 ^ (row & 7));
      wsh[dst] = *(const int4*)(W + (long)(n0 + row) * 256 + k0 + c16 * 8);
    }
    __syncthreads();
#pragma unroll
    for (int kk = 0; kk < 2; ++kk) {
      bs8 af[4], wf[4];
#pragma unroll
      for (int m = 0; m < 4; ++m) {
        const int row = wm + m * 16 + lr;
        af[m] = *(const bs8*)&ash[(row << 3) | ((kk * 4 + lk) ^ (row & 7))];
      }
#pragma unroll
      for (int n = 0; n < 4; ++n) {
        const int row = wn + n * 16 + lr;
        wf[n] = *(const bs8*)&wsh[(row << 3) | ((kk * 4 + lk) ^ (row & 7))];
      }
#pragma unroll
      for (int m = 0; m < 4; ++m)
#pragma unroll
        for (int n = 0; n < 4; ++n)
          acc[m][n] = __builtin_amdgcn_mfma_f32_16x16x32_bf16(af[m], wf[n],
                                                              acc[m][n], 0, 0, 0);
    }
  }
  // epilogue
#pragma unroll
  for (int m = 0; m < 4; ++m) {
    const int rb = m0 + wm + m * 16 + lk * 4;
#pragma unroll
    for (int n = 0; n < 4; ++n) {
      const int gc = n0 + wn + n * 16 + lr;
      const float bv = bias[gc];
#pragma unroll
      for (int j = 0; j < 4; ++j) {
        const long idx = (long)(rb + j) * 256 + gc;
        float v = acc[m][n][j] + bv;
        if constexpr (EPI == EPI_GELU)
          v = 0.5f * v * (1.f + erff(v * 0.70710678118654752f));
        if constexpr (EPI == EPI_PLAIN || EPI == EPI_GELU) {
          outb[idx] = f2bf(v);
        } else {
          const float sc = scores[(long)(rb + j) * 4 + expert];  // (M,4)
          float base;
          if constexpr (EPI == EPI_CINIT) base = csrc[idx];
          else                            base = outf[idx];
          outf[idx] = base + sc * v;
        }
      }
    }
  }
}

// ---------------------------------------------------------------------------
// softmax over each contiguous 32-group (feature-dim softmax per head)
// groups align with 32-lane half-waves: shfl_xor masks 16..1 stay in-group.
// ---------------------------------------------------------------------------
__global__ void softmax32k(u16* __restrict__ x) {
  const long n = 8388608;  // M*256
  const long stride = (long)gridDim.x * blockDim.x;
  for (long i = (long)blockIdx.x * blockDim.x + threadIdx.x; i < n; i += stride) {
    const float v = bf2f(x[i]);
    float mx = v;
#pragma unroll
    for (int o = 16; o >= 1; o >>= 1) mx = fmaxf(mx, __shfl_xor(mx, o));
    const float p = __expf(v - mx);
    float s = p;
#pragma unroll
    for (int o = 16; o >= 1; o >>= 1) s += __shfl_xor(s, o);
    x[i] = f2bf(p / s);
  }
}

// ---------------------------------------------------------------------------
// stats: rows of kpre/vpre (pre-softmax k, v; bf16, (B*8192, 256)) ->
// per-block partial ksum[256] and tmp[h][dk][dv] (8192).  Thread t=(h,dk)
// owns tmp row in 32 registers; v[h][dv] fetched via wave shfl (no LDS).
// grid = (64 chunks, B); 128 rows/chunk.
// ---------------------------------------------------------------------------
__global__ __launch_bounds__(256) void stats256(const u16* __restrict__ kp,
                                                const u16* __restrict__ vp,
                                                float* __restrict__ pk,
                                                float* __restrict__ pt) {
  const int t = threadIdx.x, lane = t & 63;
  const int b = blockIdx.y, ch = blockIdx.x;
  const long rbase = (long)b * 8192 + (long)ch * 128;
  float ks = 0.f, ta[32];
#pragma unroll
  for (int i = 0; i < 32; ++i) ta[i] = 0.f;
  for (int r = 0; r < 128; ++r) {
    const long off = (rbase + r) * 256 + t;
    const float kv = bf2f(kp[off]);
    const float vv = bf2f(vp[off]);
    float mx = kv;
#pragma unroll
    for (int o = 16; o >= 1; o >>= 1) mx = fmaxf(mx, __shfl_xor(mx, o));
    const float p = __expf(kv - mx);
    float s = p;
#pragma unroll
    for (int o = 16; o >= 1; o >>= 1) s += __shfl_xor(s, o);
    const float kn = p / s;
    ks += kn;
#pragma unroll
    for (int dv = 0; dv < 32; ++dv) {
      const float vs = __shfl(vv, (lane & 32) | dv);
      ta[dv] += kn * vs;
    }
  }
  const int blk = b * gridDim.x + ch;
  pk[(long)blk * 256 + t] = ks;
  float* po = pt + (long)blk * 8192 + (long)t * 32;
#pragma unroll
  for (int dv = 0; dv < 32; ++dv) po[dv] = ta[dv];
}

// deterministic tree-reduce of the 64 chunk-partials per (f,b)
__global__ void reduceStats(const float* __restrict__ pk,
                            const float* __restrict__ pt,
                            float* __restrict__ ksum, float* __restrict__ tmp) {
  const int fb = blockIdx.y;
  const int i = blockIdx.x * 256 + threadIdx.x;  // 0..8447
  float s = 0.f;
  if (i < 256) {
    const float* p = pk + (long)fb * 64 * 256 + i;
    for (int c = 0; c < 64; ++c) s += p[c * 256];
    ksum[(long)fb * 256 + i] = s;
  } else {
    const int j = i - 256;
    const float* p = pt + (long)fb * 64 * 8192 + j;
    for (int c = 0; c < 64; ++c) s += p[c * 8192];
    tmp[(long)fb * 8192 + j] = s;
  }
}

// ---------------------------------------------------------------------------
// mix: out = q + mean_f( alpha_f * (q @ tmp_f) ), alpha_f = 1/dot(q_h,ksum_f_h)
// tmp/ksum staged in LDS once per block; q values moved via wave shfl.
// grid = (LQ/128, B).
// ---------------------------------------------------------------------------
template <int F>
__global__ __launch_bounds__(256) void mixk(const u16* __restrict__ q,
                                            const float* __restrict__ ksum,
                                            const float* __restrict__ tmp,
                                            u16* __restrict__ out) {
  __shared__ float tsh[F * 8192];
  __shared__ float ksh[F * 256];
  const int t = threadIdx.x, lane = t & 63;
  const int h = t >> 5, dv = t & 31;
  const int b = blockIdx.y;
  for (int f = 0; f < F; ++f) {
    for (int i = t; i < 8192; i += 256) tsh[f * 8192 + i] = tmp[((long)f * 4 + b) * 8192 + i];
    if (t < 256) ksh[f * 256 + t] = ksum[((long)f * 4 + b) * 256 + t];
  }
  __syncthreads();
  const long row0 = (long)b * 8192 + (long)blockIdx.x * 128;
  for (int r = 0; r < 128; ++r) {
    const long row = row0 + r;
    const float qv = bf2f(q[row * 256 + t]);
    float accv = 0.f;
    for (int f = 0; f < F; ++f) {
      float ap = qv * ksh[f * 256 + t];
#pragma unroll
      for (int o = 16; o >= 1; o >>= 1) ap += __shfl_xor(ap, o);
      const float alpha = 1.0f / ap;
      float o2 = 0.f;
#pragma unroll
      for (int dk = 0; dk < 32; ++dk) {
        const float qk = __shfl(qv, (lane & 32) | dk);
        o2 += qk * tsh[f * 8192 + h * 1024 + dk * 32 + dv];
      }
      accv += alpha * o2;
    }
    out[row * 256 + t] = f2bf(qv + accv * (1.0f / (float)F));
  }
}

// pre-convert the 34 (256x256) weight matrices to bf16 in one launch
struct WTab { const float* p[34]; };
__global__ void convW(WTab tab, u16* __restrict__ dst) {
  const int s = blockIdx.y;
  const long i = ((long)blockIdx.x * 256 + threadIdx.x) * 4;
  const float4 v = *(const float4*)(tab.p[s] + i);
  ushort4 o;
  o.x = f2bf(v.x); o.y = f2bf(v.y); o.z = f2bf(v.z); o.w = f2bf(v.w);
  *(ushort4*)(dst + (long)s * 65536 + i) = o;
}

// ---------------------------------------------------------------------------
extern "C" void kernel_launch(void* const* d_in, const int* in_sizes, int n_in,
                              void* d_out, int out_size, void* d_ws, size_t ws_size,
                              hipStream_t stream) {
  (void)in_sizes; (void)n_in; (void)out_size; (void)ws_size;
  const float* scores = (const float*)d_in[0];
  const float* query  = (const float*)d_in[1];
  const float* IF     = (const float*)d_in[2];
  const float* ca_Wq = (const float*)d_in[3];  const float* ca_bq = (const float*)d_in[4];
  const float* ca_Wk = (const float*)d_in[5];  const float* ca_bk = (const float*)d_in[6];
  const float* ca_Wv = (const float*)d_in[7];  const float* ca_bv = (const float*)d_in[8];
  const float* ca_Wo = (const float*)d_in[9];  const float* ca_bo = (const float*)d_in[10];
  const float* sa_Wq = (const float*)d_in[11]; const float* sa_bq = (const float*)d_in[12];
  const float* sa_Wk = (const float*)d_in[13]; const float* sa_bk = (const float*)d_in[14];
  const float* sa_Wv = (const float*)d_in[15]; const float* sa_bv = (const float*)d_in[16];
  const float* sa_Wo = (const float*)d_in[17]; const float* sa_bo = (const float*)d_in[18];
  const float* f1W1 = (const float*)d_in[19]; const float* f1b1 = (const float*)d_in[20];
  const float* f1W2 = (const float*)d_in[21]; const float* f1b2 = (const float*)d_in[22];
  const float* f1W3 = (const float*)d_in[23]; const float* f1b3 = (const float*)d_in[24];
  const float* f2W1 = (const float*)d_in[25]; const float* f2b1 = (const float*)d_in[26];
  const float* f2W2 = (const float*)d_in[27]; const float* f2b2 = (const float*)d_in[28];
  const float* f2W3 = (const float*)d_in[29]; const float* f2b3 = (const float*)d_in[30];

  char* ws = (char*)d_ws;
  u16* X0 = (u16*)(ws);               // (M,256) bf16 slots, 16 MiB each
  u16* X1 = (u16*)(ws + 16777216);
  u16* X2 = (u16*)(ws + 33554432);
  u16* X3 = (u16*)(ws + 50331648);
  u16* W16 = (u16*)(ws + 67108864);   // 34 * 65536 bf16
  float* ksum = (float*)(ws + 71565312);  // [F*B][256]
  float* tmpb = (float*)(ws + 71573504);  // [F*B][8192]
  float* pks  = (float*)(ws + 71835648);  // partials
  float* ptm  = (float*)(ws + 72359936);
  float* qacc = (float*)d_out;        // fp32 accumulator doubles as output

  WTab tab;
  tab.p[0] = ca_Wq; tab.p[1] = ca_Wk; tab.p[2] = ca_Wk + 65536;
  tab.p[3] = ca_Wv; tab.p[4] = ca_Wv + 65536; tab.p[5] = ca_Wo;
  tab.p[6] = sa_Wq; tab.p[7] = sa_Wk; tab.p[8] = sa_Wv; tab.p[9] = sa_Wo;
  for (int e = 0; e < 4; ++e) {
    tab.p[10 + e] = f1W1 + e * 65536; tab.p[14 + e] = f1W2 + e * 65536;
    tab.p[18 + e] = f1W3 + e * 65536; tab.p[22 + e] = f2W1 + e * 65536;
    tab.p[26 + e] = f2W2 + e * 65536; tab.p[30 + e] = f2W3 + e * 65536;
  }
  convW<<<dim3(64, 34), 256, 0, stream>>>(tab, W16);

  const dim3 gg(256, 2), gb(256);
  // ---- cross attention ----
  gemm256<true, EPI_PLAIN><<<gg, gb, 0, stream>>>(query, W16 + 0 * 65536L, ca_bq, X0, nullptr, nullptr, nullptr, 0);
  softmax32k<<<8192, 256, 0, stream>>>(X0);  // q
  for (int f = 0; f < 2; ++f) {
    gemm256<true, EPI_PLAIN><<<gg, gb, 0, stream>>>(IF + (long)f * 8388608, W16 + (1 + f) * 65536L, ca_bk + f * 256, X1, nullptr, nullptr, nullptr, 0);
    gemm256<true, EPI_PLAIN><<<gg, gb, 0, stream>>>(IF + (long)f * 8388608, W16 + (3 + f) * 65536L, ca_bv + f * 256, X2, nullptr, nullptr, nullptr, 0);
    stats256<<<dim3(64, 4), 256, 0, stream>>>(X1, X2, pks + (long)f * 4 * 64 * 256, ptm + (long)f * 4 * 64 * 8192);
  }
  reduceStats<<<dim3(33, 8), 256, 0, stream>>>(pks, ptm, ksum, tmpb);
  mixk<2><<<dim3(64, 4), 256, 0, stream>>>(X0, ksum, tmpb, X1);      // ca_in = q + mean_f(...)
  gemm256<false, EPI_PLAIN><<<gg, gb, 0, stream>>>(X1, W16 + 5 * 65536L, ca_bo, X2, nullptr, nullptr, nullptr, 0);  // ca
  for (int e = 0; e < 4; ++e) {  // FFN1 + combine into qacc (=d_out), init from query
    gemm256<false, EPI_GELU><<<gg, gb, 0, stream>>>(X2, W16 + (10 + e) * 65536L, f1b1 + e * 256, X0, nullptr, nullptr, nullptr, 0);
    gemm256<false, EPI_GELU><<<gg, gb, 0, stream>>>(X0, W16 + (14 + e) * 65536L, f1b2 + e * 256, X3, nullptr, nullptr, nullptr, 0);
    if (e == 0)
      gemm256<false, EPI_CINIT><<<gg, gb, 0, stream>>>(X3, W16 + (18 + e) * 65536L, f1b3 + e * 256, nullptr, qacc, query, scores, e);
    else
      gemm256<false, EPI_CACC><<<gg, gb, 0, stream>>>(X3, W16 + (18 + e) * 65536L, f1b3 + e * 256, nullptr, qacc, nullptr, scores, e);
  }
  // ---- self attention (input = qacc fp32) ----
  gemm256<true, EPI_PLAIN><<<gg, gb, 0, stream>>>(qacc, W16 + 6 * 65536L, sa_bq, X0, nullptr, nullptr, nullptr, 0);
  softmax32k<<<8192, 256, 0, stream>>>(X0);  // q2
  gemm256<true, EPI_PLAIN><<<gg, gb, 0, stream>>>(qacc, W16 + 7 * 65536L, sa_bk, X1, nullptr, nullptr, nullptr, 0);
  gemm256<true, EPI_PLAIN><<<gg, gb, 0, stream>>>(qacc, W16 + 8 * 65536L, sa_bv, X2, nullptr, nullptr, nullptr, 0);
  stats256<<<dim3(64, 4), 256, 0, stream>>>(X1, X2, pks, ptm);
  reduceStats<<<dim3(33, 4), 256, 0, stream>>>(pks, ptm, ksum, tmpb);
  mixk<1><<<dim3(64, 4), 256, 0, stream>>>(X0, ksum, tmpb, X1);
  gemm256<false, EPI_PLAIN><<<gg, gb, 0, stream>>>(X1, W16 + 9 * 65536L, sa_bo, X2, nullptr, nullptr, nullptr, 0);  // sa
  for (int e = 0; e < 4; ++e) {  // FFN2 + combine: d_out = qacc + sum_e score_e * o_e (in place)
    gemm256<false, EPI_GELU><<<gg, gb, 0, stream>>>(X2, W16 + (22 + e) * 65536L, f2b1 + e * 256, X0, nullptr, nullptr, nullptr, 0);
    gemm256<false, EPI_GELU><<<gg, gb, 0, stream>>>(X0, W16 + (26 + e) * 65536L, f2b2 + e * 256, X3, nullptr, nullptr, nullptr, 0);
    if (e == 0)
      gemm256<false, EPI_CINIT><<<gg, gb, 0, stream>>>(X3, W16 + (30 + e) * 65536L, f2b3 + e * 256, nullptr, qacc, qacc, scores, e);
    else
      gemm256<false, EPI_CACC><<<gg, gb, 0, stream>>>(X3, W16 + (30 + e) * 65536L, f2b3 + e * 256, nullptr, qacc, nullptr, scores, e);
  }
}

// Round 2
// 709.651 us; speedup vs baseline: 1.4926x; 1.4926x over previous
//
#include <hip/hip_runtime.h>

// ---------------------------------------------------------------------------
// HeterogeneousNormalizedAttentionBlock on MI355X (gfx950)
// B=4, LQ=LK=8192, E=256, H=8, D=32, NF=2, NE=4, HID=256;  M = B*LQ = 32768
// ---------------------------------------------------------------------------

typedef unsigned short u16;
typedef __attribute__((ext_vector_type(8))) short   bs8;    // 8 x bf16
typedef __attribute__((ext_vector_type(4))) float   f32x4;
typedef __attribute__((ext_vector_type(16))) float  f32x16;

__device__ __forceinline__ float bf2f(u16 u) {
  union { float f; unsigned i; } c; c.i = ((unsigned)u) << 16; return c.f;
}
__device__ __forceinline__ u16 f2bf(float f) {
  union { float f; unsigned i; } c; c.f = f;
  unsigned x = c.i;
  return (u16)((x + 0x7fffu + ((x >> 16) & 1u)) >> 16);   // RNE
}
__device__ __forceinline__ unsigned pack2(float a, float b) {
  return (unsigned)f2bf(a) | ((unsigned)f2bf(b) << 16);
}

#define EPI_PLAIN 0
#define EPI_GELU  1
#define EPI_CINIT 2
#define EPI_CACC  3
#define EPI_QSM   4   // feature-dim softmax over 32-col head groups

// ---------------------------------------------------------------------------
// Workhorse GEMM: C(M,256) = epi(A(M,256) @ W(256,256)^T + bias)
// BM=BN=128, BK=64, 4 waves (2x2), wave 64x64. XOR-swizzled LDS.
// ---------------------------------------------------------------------------
template <bool AF32, int EPI>
__global__ __launch_bounds__(256, 2) void gemm256(
    const void* __restrict__ Ain, const u16* __restrict__ W,
    const float* __restrict__ bias, u16* __restrict__ outb,
    float* __restrict__ outf, const float* __restrict__ csrc,
    const float* __restrict__ scores, int expert) {
  __shared__ int4 ash[1024];  // 128 x 64 bf16, swizzled
  __shared__ int4 wsh[1024];
  const int tid = threadIdx.x;
  const int m0 = blockIdx.x * 128, n0 = blockIdx.y * 128;
  const int wave = tid >> 6, lane = tid & 63;
  const int wm = (wave >> 1) * 64, wn = (wave & 1) * 64;
  const int lr = lane & 15, lk = lane >> 4;
  f32x4 acc[4][4];
#pragma unroll
  for (int m = 0; m < 4; ++m)
#pragma unroll
    for (int n = 0; n < 4; ++n) acc[m][n] = f32x4{0.f, 0.f, 0.f, 0.f};

  const float* Af = (const float*)Ain;
  const u16*   Ab = (const u16*)Ain;

  for (int kt = 0; kt < 4; ++kt) {
    const int k0 = kt * 64;
    if (kt) __syncthreads();
#pragma unroll
    for (int it = 0; it < 4; ++it) {
      const int s = tid + it * 256;
      const int row = s >> 3, c16 = s & 7;
      const int dst = (row << 3) | (c16 ^ (row & 7));
      const long src = (long)(m0 + row) * 256 + k0 + c16 * 8;
      int4 val;
      if constexpr (AF32) {
        const float4* p = (const float4*)(Af + src);
        const float4 x = p[0], y = p[1];
        val.x = pack2(x.x, x.y); val.y = pack2(x.z, x.w);
        val.z = pack2(y.x, y.y); val.w = pack2(y.z, y.w);
      } else {
        val = *(const int4*)(Ab + src);
      }
      ash[dst] = val;
    }
#pragma unroll
    for (int it = 0; it < 4; ++it) {
      const int s = tid + it * 256;
      const int row = s >> 3, c16 = s & 7;
      const int dst = (row << 3) | (c16 ^ (row & 7));
      wsh[dst] = *(const int4*)(W + (long)(n0 + row) * 256 + k0 + c16 * 8);
    }
    __syncthreads();
#pragma unroll
    for (int kk = 0; kk < 2; ++kk) {
      bs8 af[4], wf[4];
#pragma unroll
      for (int m = 0; m < 4; ++m) {
        const int row = wm + m * 16 + lr;
        af[m] = *(const bs8*)&ash[(row << 3) | ((kk * 4 + lk) ^ (row & 7))];
      }
#pragma unroll
      for (int n = 0; n < 4; ++n) {
        const int row = wn + n * 16 + lr;
        wf[n] = *(const bs8*)&wsh[(row << 3) | ((kk * 4 + lk) ^ (row & 7))];
      }
#pragma unroll
      for (int m = 0; m < 4; ++m)
#pragma unroll
        for (int n = 0; n < 4; ++n)
          acc[m][n] = __builtin_amdgcn_mfma_f32_16x16x32_bf16(af[m], wf[n],
                                                              acc[m][n], 0, 0, 0);
    }
  }
  // ---- epilogue ----
  if constexpr (EPI == EPI_QSM) {
    // softmax over each head's 32 cols: frags (2hh, 2hh+1) x 16 lanes lr
#pragma unroll
    for (int m = 0; m < 4; ++m) {
      const int rb = m0 + wm + m * 16 + lk * 4;
#pragma unroll
      for (int j = 0; j < 4; ++j) {
#pragma unroll
        for (int hh = 0; hh < 2; ++hh) {
          const int c0 = n0 + wn + (2 * hh) * 16 + lr;
          float v0 = acc[m][2 * hh][j] + bias[c0];
          float v1 = acc[m][2 * hh + 1][j] + bias[c0 + 16];
          float mx = fmaxf(v0, v1);
#pragma unroll
          for (int o = 8; o >= 1; o >>= 1) mx = fmaxf(mx, __shfl_xor(mx, o));
          const float p0 = __expf(v0 - mx), p1 = __expf(v1 - mx);
          float s = p0 + p1;
#pragma unroll
          for (int o = 8; o >= 1; o >>= 1) s += __shfl_xor(s, o);
          const float inv = 1.0f / s;
          outb[(long)(rb + j) * 256 + c0]      = f2bf(p0 * inv);
          outb[(long)(rb + j) * 256 + c0 + 16] = f2bf(p1 * inv);
        }
      }
    }
  } else {
#pragma unroll
    for (int m = 0; m < 4; ++m) {
      const int rb = m0 + wm + m * 16 + lk * 4;
#pragma unroll
      for (int n = 0; n < 4; ++n) {
        const int gc = n0 + wn + n * 16 + lr;
        const float bv = bias[gc];
#pragma unroll
        for (int j = 0; j < 4; ++j) {
          const long idx = (long)(rb + j) * 256 + gc;
          float v = acc[m][n][j] + bv;
          if constexpr (EPI == EPI_GELU)
            v = 0.5f * v * (1.f + erff(v * 0.70710678118654752f));
          if constexpr (EPI == EPI_PLAIN || EPI == EPI_GELU) {
            outb[idx] = f2bf(v);
          } else {
            const float sc = scores[(long)(rb + j) * 4 + expert];
            float base;
            if constexpr (EPI == EPI_CINIT) base = csrc[idx];
            else                            base = outf[idx];
            outf[idx] = base + sc * v;
          }
        }
      }
    }
  }
}

// ---------------------------------------------------------------------------
// kvstats: fused {K-proj, V-proj, K-softmax, per-head stats}.
// Block: 64 rows x full N=256 for both K and V. 16 waves (8 K, 8 V), each
// 32x64 tile (acc[2][4]).  After GEMM: K-waves softmax rows in-register,
// both store transposed bf16 tiles into LDS (pitch 72 u16 = 144B -> col*36
// mod 32 spreads bank quads; conflict-free b128 column reads).  Then 8 waves
// run mfma_32x32x16: tmp_h = Kn_h^T @ V_h, ksum_h = Kn_h^T @ ones.
// Partials (per block) -> pks/ptm, reduced by reduceStats.
// ---------------------------------------------------------------------------
__global__ __launch_bounds__(1024, 4) void kvstats(
    const float* __restrict__ Ain, const u16* __restrict__ Wk,
    const u16* __restrict__ Wv, const float* __restrict__ bk,
    const float* __restrict__ bv, float* __restrict__ pks,
    float* __restrict__ ptm) {
  __shared__ __align__(16) char smem[73728];
  int4* ash  = (int4*)smem;        // 512 slots  (64x64 bf16)
  int4* wksh = ash + 512;          // 2048 slots (256x64)
  int4* wvsh = wksh + 2048;        // 2048 slots
  u16* KnT = (u16*)smem;           // [256][72] bf16 (transposed, padded)
  u16* VT  = KnT + 256 * 72;
  const int tid = threadIdx.x;
  const int wave = tid >> 6, lane = tid & 63;
  const int lr = lane & 15, lk = lane >> 4;
  const int kvsel = wave >> 3, w3 = wave & 7;
  const int wm = (w3 >> 2) * 32, wn = (w3 & 3) * 64;
  const int b = blockIdx.y, ch = blockIdx.x;
  const long r0 = (long)b * 8192 + (long)ch * 64;

  f32x4 acc[2][4];
#pragma unroll
  for (int m = 0; m < 2; ++m)
#pragma unroll
    for (int n = 0; n < 4; ++n) acc[m][n] = f32x4{0.f, 0.f, 0.f, 0.f};

  for (int kt = 0; kt < 4; ++kt) {
    const int k0 = kt * 64;
    if (kt) __syncthreads();
    if (tid < 512) {  // A tile 64x64 fp32 -> bf16
      const int row = tid >> 3, c16 = tid & 7;
      const int dst = (row << 3) | (c16 ^ (row & 7));
      const float4* p = (const float4*)(Ain + (r0 + row) * 256 + k0 + c16 * 8);
      const float4 x = p[0], y = p[1];
      int4 val;
      val.x = pack2(x.x, x.y); val.y = pack2(x.z, x.w);
      val.z = pack2(y.x, y.y); val.w = pack2(y.z, y.w);
      ash[dst] = val;
    }
#pragma unroll
    for (int it = 0; it < 2; ++it) {  // Wk + Wv tiles 256x64
      const int s = tid + it * 1024;
      const int row = s >> 3, c16 = s & 7;
      const int dst = (row << 3) | (c16 ^ (row & 7));
      wksh[dst] = *(const int4*)(Wk + (long)row * 256 + k0 + c16 * 8);
      wvsh[dst] = *(const int4*)(Wv + (long)row * 256 + k0 + c16 * 8);
    }
    __syncthreads();
    const int4* wsh = kvsel ? wvsh : wksh;
#pragma unroll
    for (int kk = 0; kk < 2; ++kk) {
      bs8 af[2], wf[4];
#pragma unroll
      for (int m = 0; m < 2; ++m) {
        const int row = wm + m * 16 + lr;
        af[m] = *(const bs8*)&ash[(row << 3) | ((kk * 4 + lk) ^ (row & 7))];
      }
#pragma unroll
      for (int n = 0; n < 4; ++n) {
        const int row = wn + n * 16 + lr;
        wf[n] = *(const bs8*)&wsh[(row << 3) | ((kk * 4 + lk) ^ (row & 7))];
      }
#pragma unroll
      for (int m = 0; m < 2; ++m)
#pragma unroll
        for (int n = 0; n < 4; ++n)
          acc[m][n] = __builtin_amdgcn_mfma_f32_16x16x32_bf16(af[m], wf[n],
                                                              acc[m][n], 0, 0, 0);
    }
  }
  __syncthreads();  // GEMM LDS dead; reuse as KnT/VT

  const float* bias = kvsel ? bv : bk;
  if (kvsel == 0) {
    // softmax each (row, head) across 16 lanes x 2 frags
#pragma unroll
    for (int m = 0; m < 2; ++m)
#pragma unroll
      for (int j = 0; j < 4; ++j)
#pragma unroll
        for (int hh = 0; hh < 2; ++hh) {
          const int c0 = wn + (2 * hh) * 16 + lr;
          float v0 = acc[m][2 * hh][j] + bias[c0];
          float v1 = acc[m][2 * hh + 1][j] + bias[c0 + 16];
          float mx = fmaxf(v0, v1);
#pragma unroll
          for (int o = 8; o >= 1; o >>= 1) mx = fmaxf(mx, __shfl_xor(mx, o));
          const float p0 = __expf(v0 - mx), p1 = __expf(v1 - mx);
          float s = p0 + p1;
#pragma unroll
          for (int o = 8; o >= 1; o >>= 1) s += __shfl_xor(s, o);
          const float inv = 1.0f / s;
          acc[m][2 * hh][j] = p0 * inv;
          acc[m][2 * hh + 1][j] = p1 * inv;
        }
  }
  {
    u16* T = kvsel ? VT : KnT;
#pragma unroll
    for (int m = 0; m < 2; ++m) {
      const int rb = wm + m * 16 + lk * 4;
#pragma unroll
      for (int n = 0; n < 4; ++n) {
        const int col = wn + n * 16 + lr;
        float v0 = acc[m][n][0], v1 = acc[m][n][1];
        float v2 = acc[m][n][2], v3 = acc[m][n][3];
        if (kvsel) {
          const float bb = bias[col];
          v0 += bb; v1 += bb; v2 += bb; v3 += bb;
        }
        uint2 w;
        w.x = pack2(v0, v1); w.y = pack2(v2, v3);
        *(uint2*)(T + col * 72 + rb) = w;
      }
    }
  }
  __syncthreads();

  if (kvsel == 0) {  // stats: wave w3 = head h
    const int h = w3;
    f32x16 aT, aK;
#pragma unroll
    for (int r = 0; r < 16; ++r) { aT[r] = 0.f; aK[r] = 0.f; }
    bs8 ones;
#pragma unroll
    for (int e = 0; e < 8; ++e) ones[e] = (short)0x3F80;
    const u16* kcol = KnT + (h * 32 + (lane & 31)) * 72;
    const u16* vcol = VT  + (h * 32 + (lane & 31)) * 72;
    const int hi8 = (lane >> 5) * 8;
#pragma unroll
    for (int ks = 0; ks < 4; ++ks) {
      const bs8 a  = *(const bs8*)(kcol + ks * 16 + hi8);
      const bs8 vb = *(const bs8*)(vcol + ks * 16 + hi8);
      aT = __builtin_amdgcn_mfma_f32_32x32x16_bf16(a, vb, aT, 0, 0, 0);
      aK = __builtin_amdgcn_mfma_f32_32x32x16_bf16(a, ones, aK, 0, 0, 0);
    }
    const long blk = (long)b * gridDim.x + ch;
    float* po = ptm + blk * 8192 + h * 1024;
#pragma unroll
    for (int r = 0; r < 16; ++r) {
      const int dk = (r & 3) + 8 * (r >> 2) + 4 * (lane >> 5);
      po[dk * 32 + (lane & 31)] = aT[r];
    }
    if ((lane & 31) == 0) {
#pragma unroll
      for (int r = 0; r < 16; ++r) {
        const int dk = (r & 3) + 8 * (r >> 2) + 4 * (lane >> 5);
        pks[blk * 256 + h * 32 + dk] = aK[r];
      }
    }
  }
}

// deterministic reduce of the 128 chunk-partials for ONE f
__global__ void reduceStats(const float* __restrict__ pk,
                            const float* __restrict__ pt,
                            float* __restrict__ ksum, float* __restrict__ tmp) {
  const int b = blockIdx.y;
  const int i = blockIdx.x * 256 + threadIdx.x;  // 0..8447
  float s = 0.f;
  if (i < 256) {
    const float* p = pk + (long)b * 128 * 256 + i;
    for (int c = 0; c < 128; ++c) s += p[c * 256];
    ksum[(long)b * 256 + i] = s;
  } else {
    const int j = i - 256;
    const float* p = pt + (long)b * 128 * 8192 + j;
    for (int c = 0; c < 128; ++c) s += p[c * 8192];
    tmp[(long)b * 8192 + j] = s;
  }
}

// ---------------------------------------------------------------------------
// mix: out = q + mean_f( (q @ tmp_f) / dot(q_h, ksum_f_h) )
// tmp column hoisted to registers; 2-row ILP; 1024 blocks.
// ---------------------------------------------------------------------------
template <int F>
__global__ __launch_bounds__(256) void mixk(const u16* __restrict__ q,
                                            const float* __restrict__ ksum,
                                            const float* __restrict__ tmp,
                                            u16* __restrict__ out) {
  const int t = threadIdx.x, lane = t & 63;
  const int h = t >> 5, dv = t & 31;
  const int b = blockIdx.y;
  float tr[F][32], ks[F];
#pragma unroll
  for (int f = 0; f < F; ++f) {
    const float* tp = tmp + ((long)f * 4 + b) * 8192 + h * 1024 + dv;
#pragma unroll
    for (int dk = 0; dk < 32; ++dk) tr[f][dk] = tp[dk * 32];
    ks[f] = ksum[((long)f * 4 + b) * 256 + t];
  }
  const long row0 = (long)b * 8192 + (long)blockIdx.x * 32;
  for (int r = 0; r < 32; r += 2) {
    float qv[2];
    qv[0] = bf2f(q[(row0 + r) * 256 + t]);
    qv[1] = bf2f(q[(row0 + r + 1) * 256 + t]);
    float ap[2][F];
#pragma unroll
    for (int u = 0; u < 2; ++u)
#pragma unroll
      for (int f = 0; f < F; ++f) ap[u][f] = qv[u] * ks[f];
#pragma unroll
    for (int o = 16; o >= 1; o >>= 1)
#pragma unroll
      for (int u = 0; u < 2; ++u)
#pragma unroll
        for (int f = 0; f < F; ++f) ap[u][f] += __shfl_xor(ap[u][f], o);
    float o2[2][F];
#pragma unroll
    for (int u = 0; u < 2; ++u)
#pragma unroll
      for (int f = 0; f < F; ++f) o2[u][f] = 0.f;
#pragma unroll
    for (int dk = 0; dk < 32; ++dk) {
      const int src = (lane & 32) | dk;
      const float qk0 = __shfl(qv[0], src);
      const float qk1 = __shfl(qv[1], src);
#pragma unroll
      for (int f = 0; f < F; ++f) {
        o2[0][f] += qk0 * tr[f][dk];
        o2[1][f] += qk1 * tr[f][dk];
      }
    }
#pragma unroll
    for (int u = 0; u < 2; ++u) {
      float a = 0.f;
#pragma unroll
      for (int f = 0; f < F; ++f) a += o2[u][f] / ap[u][f];
      out[(row0 + r + u) * 256 + t] = f2bf(qv[u] + a * (1.0f / (float)F));
    }
  }
}

// pre-convert the 34 (256x256) weight matrices to bf16
struct WTab { const float* p[34]; };
__global__ void convW(WTab tab, u16* __restrict__ dst) {
  const int s = blockIdx.y;
  const long i = ((long)blockIdx.x * 256 + threadIdx.x) * 4;
  const float4 v = *(const float4*)(tab.p[s] + i);
  ushort4 o;
  o.x = f2bf(v.x); o.y = f2bf(v.y); o.z = f2bf(v.z); o.w = f2bf(v.w);
  *(ushort4*)(dst + (long)s * 65536 + i) = o;
}

// ---------------------------------------------------------------------------
extern "C" void kernel_launch(void* const* d_in, const int* in_sizes, int n_in,
                              void* d_out, int out_size, void* d_ws, size_t ws_size,
                              hipStream_t stream) {
  (void)in_sizes; (void)n_in; (void)out_size; (void)ws_size;
  const float* scores = (const float*)d_in[0];
  const float* query  = (const float*)d_in[1];
  const float* IF     = (const float*)d_in[2];
  const float* ca_Wq = (const float*)d_in[3];  const float* ca_bq = (const float*)d_in[4];
  const float* ca_Wk = (const float*)d_in[5];  const float* ca_bk = (const float*)d_in[6];
  const float* ca_Wv = (const float*)d_in[7];  const float* ca_bv = (const float*)d_in[8];
  const float* ca_Wo = (const float*)d_in[9];  const float* ca_bo = (const float*)d_in[10];
  const float* sa_Wq = (const float*)d_in[11]; const float* sa_bq = (const float*)d_in[12];
  const float* sa_Wk = (const float*)d_in[13]; const float* sa_bk = (const float*)d_in[14];
  const float* sa_Wv = (const float*)d_in[15]; const float* sa_bv = (const float*)d_in[16];
  const float* sa_Wo = (const float*)d_in[17]; const float* sa_bo = (const float*)d_in[18];
  const float* f1W1 = (const float*)d_in[19]; const float* f1b1 = (const float*)d_in[20];
  const float* f1W2 = (const float*)d_in[21]; const float* f1b2 = (const float*)d_in[22];
  const float* f1W3 = (const float*)d_in[23]; const float* f1b3 = (const float*)d_in[24];
  const float* f2W1 = (const float*)d_in[25]; const float* f2b1 = (const float*)d_in[26];
  const float* f2W2 = (const float*)d_in[27]; const float* f2b2 = (const float*)d_in[28];
  const float* f2W3 = (const float*)d_in[29]; const float* f2b3 = (const float*)d_in[30];

  char* ws = (char*)d_ws;
  u16* X0 = (u16*)(ws);                   // (M,256) bf16, 16 MiB each
  u16* X1 = (u16*)(ws + 16777216);
  u16* X2 = (u16*)(ws + 33554432);
  u16* X3 = (u16*)(ws + 50331648);        // FFN intermediate; doubles as ptm
  float* ptmX3 = (float*)(ws + 50331648); // 4b x 128ch x 8192 f32 = 16.78 MB
  u16* W16 = (u16*)(ws + 67108864);       // 34 * 65536 bf16
  float* ksum = (float*)(ws + 71565312);  // [F*B][256]
  float* tmpb = (float*)(ws + 71573504);  // [F*B][8192]
  float* pks  = (float*)(ws + 71835648);  // 4b x 128ch x 256 f32 = 0.52 MB
  float* qacc = (float*)d_out;            // fp32 accumulator = output

  WTab tab;
  tab.p[0] = ca_Wq; tab.p[1] = ca_Wk; tab.p[2] = ca_Wk + 65536;
  tab.p[3] = ca_Wv; tab.p[4] = ca_Wv + 65536; tab.p[5] = ca_Wo;
  tab.p[6] = sa_Wq; tab.p[7] = sa_Wk; tab.p[8] = sa_Wv; tab.p[9] = sa_Wo;
  for (int e = 0; e < 4; ++e) {
    tab.p[10 + e] = f1W1 + e * 65536; tab.p[14 + e] = f1W2 + e * 65536;
    tab.p[18 + e] = f1W3 + e * 65536; tab.p[22 + e] = f2W1 + e * 65536;
    tab.p[26 + e] = f2W2 + e * 65536; tab.p[30 + e] = f2W3 + e * 65536;
  }
  convW<<<dim3(64, 34), 256, 0, stream>>>(tab, W16);

  const dim3 gg(256, 2), gb(256);
  const dim3 kvg(128, 4), kvb(1024);
  // ---- cross attention ----
  gemm256<true, EPI_QSM><<<gg, gb, 0, stream>>>(query, W16 + 0 * 65536L, ca_bq, X0, nullptr, nullptr, nullptr, 0);
  for (int f = 0; f < 2; ++f) {
    kvstats<<<kvg, kvb, 0, stream>>>(IF + (long)f * 8388608,
                                     W16 + (1 + f) * 65536L, W16 + (3 + f) * 65536L,
                                     ca_bk + f * 256, ca_bv + f * 256, pks, ptmX3);
    reduceStats<<<dim3(33, 4), 256, 0, stream>>>(pks, ptmX3, ksum + f * 4 * 256, tmpb + (long)f * 4 * 8192);
  }
  mixk<2><<<dim3(256, 4), 256, 0, stream>>>(X0, ksum, tmpb, X1);
  gemm256<false, EPI_PLAIN><<<gg, gb, 0, stream>>>(X1, W16 + 5 * 65536L, ca_bo, X2, nullptr, nullptr, nullptr, 0);
  for (int e = 0; e < 4; ++e) {  // FFN1 + combine into qacc, init from query
    gemm256<false, EPI_GELU><<<gg, gb, 0, stream>>>(X2, W16 + (10 + e) * 65536L, f1b1 + e * 256, X0, nullptr, nullptr, nullptr, 0);
    gemm256<false, EPI_GELU><<<gg, gb, 0, stream>>>(X0, W16 + (14 + e) * 65536L, f1b2 + e * 256, X3, nullptr, nullptr, nullptr, 0);
    if (e == 0)
      gemm256<false, EPI_CINIT><<<gg, gb, 0, stream>>>(X3, W16 + (18 + e) * 65536L, f1b3 + e * 256, nullptr, qacc, query, scores, e);
    else
      gemm256<false, EPI_CACC><<<gg, gb, 0, stream>>>(X3, W16 + (18 + e) * 65536L, f1b3 + e * 256, nullptr, qacc, nullptr, scores, e);
  }
  // ---- self attention ----
  gemm256<true, EPI_QSM><<<gg, gb, 0, stream>>>(qacc, W16 + 6 * 65536L, sa_bq, X0, nullptr, nullptr, nullptr, 0);
  kvstats<<<kvg, kvb, 0, stream>>>(qacc, W16 + 7 * 65536L, W16 + 8 * 65536L,
                                   sa_bk, sa_bv, pks, ptmX3);
  reduceStats<<<dim3(33, 4), 256, 0, stream>>>(pks, ptmX3, ksum, tmpb);
  mixk<1><<<dim3(256, 4), 256, 0, stream>>>(X0, ksum, tmpb, X1);
  gemm256<false, EPI_PLAIN><<<gg, gb, 0, stream>>>(X1, W16 + 9 * 65536L, sa_bo, X2, nullptr, nullptr, nullptr, 0);
  for (int e = 0; e < 4; ++e) {  // FFN2 + combine (in place on qacc)
    gemm256<false, EPI_GELU><<<gg, gb, 0, stream>>>(X2, W16 + (22 + e) * 65536L, f2b1 + e * 256, X0, nullptr, nullptr, nullptr, 0);
    gemm256<false, EPI_GELU><<<gg, gb, 0, stream>>>(X0, W16 + (26 + e) * 65536L, f2b2 + e * 256, X3, nullptr, nullptr, nullptr, 0);
    if (e == 0)
      gemm256<false, EPI_CINIT><<<gg, gb, 0, stream>>>(X3, W16 + (30 + e) * 65536L, f2b3 + e * 256, nullptr, qacc, qacc, scores, e);
    else
      gemm256<false, EPI_CACC><<<gg, gb, 0, stream>>>(X3, W16 + (30 + e) * 65536L, f2b3 + e * 256, nullptr, qacc, nullptr, scores, e);
  }
}